// Round 15
// baseline (21.793 us; speedup 1.0000x reference)
//
#include <hip/hip_runtime.h>

#define N 4096
#define M 1024
#define D 64
#define MT 16                             // m-values per thread
#define SPLITS 16                         // N-chunks (champion config)
#define ROWS_PER_BLOCK (N / SPLITS)       // 256
#define ROWS_PER_WAVE  (ROWS_PER_BLOCK/4) // 64
#define NB (ROWS_PER_WAVE / 4)            // 16 four-row batches
#define SITES (M * D)                     // 65536
#define K2_BLOCKS 64

typedef float v2f __attribute__((ext_vector_type(2)));

// Register-only 3-input min (v_min3_f32), minnum semantics = fminf twice.
__device__ __forceinline__ float min3f(float a, float b, float c) {
    float d;
    asm("v_min3_f32 %0, %1, %2, %3" : "=v"(d) : "v"(a), "v"(b), "v"(c));
    return d;
}

// K1: champion structure; NEW inner loop packs the FMA side with
// v_pk_fma_f32 (2 fp32 FMAs / instruction). Per 4-row batch per m:
// 2 pk_fma + 2 min3 = 1.0 inst/site (was 1.56). IEEE fma per lane ->
// bit-identical values -> pout bit-identical to R14 champion.
__global__ __launch_bounds__(256) void k_minpart(const float* __restrict__ z,
                                                 const float* __restrict__ e,
                                                 const int* __restrict__ idx,
                                                 float* __restrict__ pout,
                                                 float* __restrict__ out,
                                                 int* __restrict__ counter) {
    const int bid = blockIdx.x;
    if (bid == 0 && threadIdx.x == 0) *counter = 0;   // reset for K2, every call

    // fused elementwise outputs: 256 elements per block
    {
        const int i = bid * 256 + (int)threadIdx.x;
        const float zv = z[i];
        const int row = i >> 6, dd = i & 63;
        out[1 + i] = (dd < idx[row]) ? zv : 0.0f;   // z_masked
        out[1 + N * D + i] = zv;                    // z_copy
    }

    const int mt   = bid & 63;    // m-tile
    const int s    = bid >> 6;    // split
    const int lane = threadIdx.x & 63;
    const int w    = threadIdx.x >> 6;
    const int m0   = mt * MT;

    v2f n2p[MT];   // (-2*e) pre-packed as {x,x} for packed fma
#pragma unroll
    for (int j = 0; j < MT; ++j) {
        const float v = -2.0f * e[(m0 + j) * D + lane];
        n2p[j] = (v2f){v, v};
    }

    float acc[MT];
#pragma unroll
    for (int j = 0; j < MT; ++j) acc[j] = 3.4e38f;

    const float* zp = z + (s * ROWS_PER_BLOCK + w * ROWS_PER_WAVE) * D + lane;

    // pipeline prologue: batch 0 loads
    float za = zp[0 * D], zb = zp[1 * D], zc = zp[2 * D], zd = zp[3 * D];

#pragma unroll
    for (int r4 = 0; r4 < NB - 1; ++r4) {   // 15 pipelined batches
        const float na = zp[(4 * r4 + 4) * D];
        const float nb = zp[(4 * r4 + 5) * D];
        const float nc = zp[(4 * r4 + 6) * D];
        const float nd = zp[(4 * r4 + 7) * D];
        const v2f zab = (v2f){za, zb}, zcd = (v2f){zc, zd};
        const v2f sab = zab * zab;          // v_pk_mul_f32
        const v2f scd = zcd * zcd;
#pragma unroll
        for (int j = 0; j < MT; ++j) {
            const v2f tab = __builtin_elementwise_fma(n2p[j], zab, sab); // pk_fma
            const v2f tcd = __builtin_elementwise_fma(n2p[j], zcd, scd); // pk_fma
            acc[j] = min3f(min3f(acc[j], tab.x, tab.y), tcd.x, tcd.y);
        }
        za = na; zb = nb; zc = nc; zd = nd;
    }
    {   // epilogue: last batch, no prefetch
        const v2f zab = (v2f){za, zb}, zcd = (v2f){zc, zd};
        const v2f sab = zab * zab;
        const v2f scd = zcd * zcd;
#pragma unroll
        for (int j = 0; j < MT; ++j) {
            const v2f tab = __builtin_elementwise_fma(n2p[j], zab, sab);
            const v2f tcd = __builtin_elementwise_fma(n2p[j], zcd, scd);
            acc[j] = min3f(min3f(acc[j], tab.x, tab.y), tcd.x, tcd.y);
        }
    }

    __shared__ float lds[4][MT * 64];
#pragma unroll
    for (int j = 0; j < MT; ++j) lds[w][j * 64 + lane] = acc[j];
    __syncthreads();
    for (int p = threadIdx.x; p < MT * 64; p += 256) {
        const float v = fminf(fminf(lds[0][p], lds[1][p]),
                              fminf(lds[2][p], lds[3][p]));
        pout[s * SITES + m0 * 64 + p] = v;   // coalesced
    }
}

// K2: R14 champion, byte-identical. Vectorized float4 split-min + e^2, sum;
// deterministic last-block finish with 64 PARALLEL coherent reads + fixed tree.
__global__ __launch_bounds__(256) void k_minsum(const float* __restrict__ pout,
                                                const float* __restrict__ e,
                                                float* __restrict__ bsums,
                                                int* __restrict__ counter,
                                                float* __restrict__ out) {
    const int t = blockIdx.x * 256 + (int)threadIdx.x;  // 16384 threads
    const int s0 = t * 4;                               // 4 consecutive sites
    float4 v = make_float4(3.4e38f, 3.4e38f, 3.4e38f, 3.4e38f);
#pragma unroll
    for (int si = 0; si < SPLITS; ++si) {
        const float4 p = *(const float4*)(pout + si * SITES + s0);
        v.x = fminf(v.x, p.x); v.y = fminf(v.y, p.y);
        v.z = fminf(v.z, p.z); v.w = fminf(v.w, p.w);
    }
    const float4 ev = *(const float4*)(e + s0);
    float local = ((v.x + ev.x * ev.x) + (v.y + ev.y * ev.y))
                + ((v.z + ev.z * ev.z) + (v.w + ev.w * ev.w));

#pragma unroll
    for (int off = 32; off > 0; off >>= 1)
        local += __shfl_down(local, off, 64);
    __shared__ float wsum[4];
    __shared__ int is_last;
    const int lane = threadIdx.x & 63, w = threadIdx.x >> 6;
    if (lane == 0) wsum[w] = local;
    __syncthreads();
    if (threadIdx.x == 0) {
        atomicExch(&bsums[blockIdx.x], (wsum[0] + wsum[1]) + (wsum[2] + wsum[3]));
        __threadfence();
        is_last = (atomicAdd(counter, 1) == K2_BLOCKS - 1);
    }
    __syncthreads();
    if (is_last && threadIdx.x < 64) {
        __threadfence();
        float v2 = atomicAdd(&bsums[threadIdx.x], 0.0f);  // 64 parallel reads
#pragma unroll
        for (int off = 32; off > 0; off >>= 1)
            v2 += __shfl_down(v2, off, 64);
        if (threadIdx.x == 0) out[0] = v2 * (1.0f / SITES);
    }
}

extern "C" void kernel_launch(void* const* d_in, const int* in_sizes, int n_in,
                              void* d_out, int out_size, void* d_ws, size_t ws_size,
                              hipStream_t stream) {
    const float* z   = (const float*)d_in[0];
    const float* e   = (const float*)d_in[1];
    const int*   idx = (const int*)d_in[2];
    float* out = (float*)d_out;

    float* pout    = (float*)d_ws;                       // 4 MB partials
    float* bsums   = (float*)d_ws + SPLITS * SITES;      // 64 floats
    int*   counter = (int*)(bsums + K2_BLOCKS);

    k_minpart<<<64 * SPLITS, 256, 0, stream>>>(z, e, idx, pout, out, counter);
    k_minsum<<<K2_BLOCKS, 256, 0, stream>>>(pout, e, bsums, counter, out);
}

// Round 16
// 20.947 us; speedup vs baseline: 1.0404x; 1.0404x over previous
//
#include <hip/hip_runtime.h>

#define N 4096
#define M 1024
#define D 64
#define MT 16                             // m-values per thread
#define SPLITS 4                          // N-chunks (was 16)
#define ROWS_PER_BLOCK (N / SPLITS)       // 1024
#define ROWS_PER_WAVE  64                 // unchanged per-wave work
#define NB (ROWS_PER_WAVE / 4)            // 16 four-row batches
#define SITES (M * D)                     // 65536
#define K2_BLOCKS 64

// Register-only 3-input min (v_min3_f32), minnum semantics = fminf twice.
__device__ __forceinline__ float min3f(float a, float b, float c) {
    float d;
    asm("v_min3_f32 %0, %1, %2, %3" : "=v"(d) : "v"(a), "v"(b), "v"(c));
    return d;
}

// K1: R14-champion math per wave, NEW geometry: 256 WGs x 1024 threads
// (16 waves) instead of 1024 WGs x 256. Same 4096 total waves, same 64 rows x
// 16 m x 64 d per wave, same 4 waves/SIMD residency — only the WG count and
// cross-wave reduce width change. Tests the WG-dispatch-cost hypothesis.
__global__ __launch_bounds__(1024) void k_minpart(const float* __restrict__ z,
                                                  const float* __restrict__ e,
                                                  const int* __restrict__ idx,
                                                  float* __restrict__ pout,
                                                  float* __restrict__ out,
                                                  int* __restrict__ counter) {
    const int bid = blockIdx.x;
    if (bid == 0 && threadIdx.x == 0) *counter = 0;   // reset for K2, every call

    // fused elementwise outputs: 1024 elements per block
    {
        const int i = bid * 1024 + (int)threadIdx.x;
        const float zv = z[i];
        const int row = i >> 6, dd = i & 63;
        out[1 + i] = (dd < idx[row]) ? zv : 0.0f;   // z_masked
        out[1 + N * D + i] = zv;                    // z_copy
    }

    const int mt   = bid & 63;    // m-tile
    const int s    = bid >> 6;    // split 0..3
    const int lane = threadIdx.x & 63;
    const int w    = threadIdx.x >> 6;   // wave 0..15
    const int m0   = mt * MT;

    float n2e[MT];
#pragma unroll
    for (int j = 0; j < MT; ++j) n2e[j] = -2.0f * e[(m0 + j) * D + lane];

    float acc[MT];
#pragma unroll
    for (int j = 0; j < MT; ++j) acc[j] = 3.4e38f;

    const float* zp = z + (s * ROWS_PER_BLOCK + w * ROWS_PER_WAVE) * D + lane;

    // pipeline prologue: batch 0 loads
    float za = zp[0 * D], zb = zp[1 * D], zc = zp[2 * D], zd = zp[3 * D];

#pragma unroll
    for (int r4 = 0; r4 < NB - 1; ++r4) {   // 15 pipelined batches
        const float na = zp[(4 * r4 + 4) * D];
        const float nb = zp[(4 * r4 + 5) * D];
        const float nc = zp[(4 * r4 + 6) * D];
        const float nd = zp[(4 * r4 + 7) * D];
        const float za2 = za * za, zb2 = zb * zb;
        const float zc2 = zc * zc, zd2 = zd * zd;
#pragma unroll
        for (int j = 0; j < MT; ++j) {
            const float t1 = fmaf(n2e[j], za, za2);
            const float t2 = fmaf(n2e[j], zb, zb2);
            const float t3 = fmaf(n2e[j], zc, zc2);
            const float t4 = fmaf(n2e[j], zd, zd2);
            acc[j] = min3f(acc[j], min3f(t1, t2, t3), t4);
        }
        za = na; zb = nb; zc = nc; zd = nd;
    }
    {   // epilogue: last batch, no prefetch
        const float za2 = za * za, zb2 = zb * zb;
        const float zc2 = zc * zc, zd2 = zd * zd;
#pragma unroll
        for (int j = 0; j < MT; ++j) {
            const float t1 = fmaf(n2e[j], za, za2);
            const float t2 = fmaf(n2e[j], zb, zb2);
            const float t3 = fmaf(n2e[j], zc, zc2);
            const float t4 = fmaf(n2e[j], zd, zd2);
            acc[j] = min3f(acc[j], min3f(t1, t2, t3), t4);
        }
    }

    // cross-wave reduce: 16 waves -> one set of 1024 sites (64 KB LDS)
    __shared__ float lds[16][MT * 64];
#pragma unroll
    for (int j = 0; j < MT; ++j) lds[w][j * 64 + lane] = acc[j];
    __syncthreads();
    {
        const int p = (int)threadIdx.x;   // one site per thread, coalesced
        float v = min3f(lds[0][p], lds[1][p], lds[2][p]);
        v = min3f(v, lds[3][p], lds[4][p]);
        v = min3f(v, lds[5][p], lds[6][p]);
        v = min3f(v, lds[7][p], lds[8][p]);
        v = min3f(v, lds[9][p], lds[10][p]);
        v = min3f(v, lds[11][p], lds[12][p]);
        v = min3f(v, lds[13][p], lds[14][p]);
        v = fminf(v, lds[15][p]);
        pout[s * SITES + m0 * 64 + p] = v;
    }
}

// K2: R14 champion, SPLITS=4. Vectorized float4 split-min + e^2, sum;
// deterministic last-block finish with 64 PARALLEL coherent reads + fixed tree.
__global__ __launch_bounds__(256) void k_minsum(const float* __restrict__ pout,
                                                const float* __restrict__ e,
                                                float* __restrict__ bsums,
                                                int* __restrict__ counter,
                                                float* __restrict__ out) {
    const int t = blockIdx.x * 256 + (int)threadIdx.x;  // 16384 threads
    const int s0 = t * 4;                               // 4 consecutive sites
    float4 v = make_float4(3.4e38f, 3.4e38f, 3.4e38f, 3.4e38f);
#pragma unroll
    for (int si = 0; si < SPLITS; ++si) {
        const float4 p = *(const float4*)(pout + si * SITES + s0);
        v.x = fminf(v.x, p.x); v.y = fminf(v.y, p.y);
        v.z = fminf(v.z, p.z); v.w = fminf(v.w, p.w);
    }
    const float4 ev = *(const float4*)(e + s0);
    float local = ((v.x + ev.x * ev.x) + (v.y + ev.y * ev.y))
                + ((v.z + ev.z * ev.z) + (v.w + ev.w * ev.w));

#pragma unroll
    for (int off = 32; off > 0; off >>= 1)
        local += __shfl_down(local, off, 64);
    __shared__ float wsum[4];
    __shared__ int is_last;
    const int lane = threadIdx.x & 63, w = threadIdx.x >> 6;
    if (lane == 0) wsum[w] = local;
    __syncthreads();
    if (threadIdx.x == 0) {
        atomicExch(&bsums[blockIdx.x], (wsum[0] + wsum[1]) + (wsum[2] + wsum[3]));
        __threadfence();
        is_last = (atomicAdd(counter, 1) == K2_BLOCKS - 1);
    }
    __syncthreads();
    if (is_last && threadIdx.x < 64) {
        __threadfence();
        float v2 = atomicAdd(&bsums[threadIdx.x], 0.0f);  // 64 parallel reads
#pragma unroll
        for (int off = 32; off > 0; off >>= 1)
            v2 += __shfl_down(v2, off, 64);
        if (threadIdx.x == 0) out[0] = v2 * (1.0f / SITES);
    }
}

extern "C" void kernel_launch(void* const* d_in, const int* in_sizes, int n_in,
                              void* d_out, int out_size, void* d_ws, size_t ws_size,
                              hipStream_t stream) {
    const float* z   = (const float*)d_in[0];
    const float* e   = (const float*)d_in[1];
    const int*   idx = (const int*)d_in[2];
    float* out = (float*)d_out;

    float* pout    = (float*)d_ws;                       // 1 MB partials
    float* bsums   = (float*)d_ws + SPLITS * SITES;      // 64 floats
    int*   counter = (int*)(bsums + K2_BLOCKS);

    k_minpart<<<64 * SPLITS, 1024, 0, stream>>>(z, e, idx, pout, out, counter);
    k_minsum<<<K2_BLOCKS, 256, 0, stream>>>(pout, e, bsums, counter, out);
}